// Round 2
// baseline (4744.754 us; speedup 1.0000x reference)
//
#include <hip/hip_runtime.h>
#include <math.h>

#define NBLK 8
#define BSZ 96
#define BATCH 2
#define CCH 768
#define HH 240
#define WW 240
#define WF 121
#define PLANE (HH*WF)          // 29040 complex per channel plane
#define NROWS (BATCH*CCH*HH)   // 368640
#define PI_D 3.14159265358979323846

// ---------- complex helpers ----------
__device__ inline float2 cmul(float2 a, float2 b){
    return make_float2(a.x*b.x - a.y*b.y, a.x*b.y + a.y*b.x);
}
__device__ inline float2 cmulc(float2 a, float2 b){ // a * conj(b)
    return make_float2(a.x*b.x + a.y*b.y, a.y*b.x - a.x*b.y);
}
__device__ inline void cfma(float2& acc, float2 a, float2 b){
    acc.x += a.x*b.x - a.y*b.y;
    acc.y += a.x*b.y + a.y*b.x;
}
__device__ inline void cfmac(float2& acc, float2 a, float2 b){ // acc += a*conj(b)
    acc.x += a.x*b.x + a.y*b.y;
    acc.y += a.y*b.x - a.x*b.y;
}

// ---------- twiddle tables: [0,256) DFT16, [256,481) DFT15, [481,721) TW240 ----------
__global__ void init_tables(float2* __restrict__ tab){
    int t = threadIdx.x;
    if (t < 256){
        int n1 = t >> 4, k1 = t & 15;
        double a = -2.0*PI_D*double((n1*k1) & 15)/16.0;
        tab[t] = make_float2((float)cos(a), (float)sin(a));
    } else if (t < 481){
        int u = t - 256; int n2 = u/15, k2 = u - n2*15;
        double a = -2.0*PI_D*double((n2*k2) % 15)/15.0;
        tab[t] = make_float2((float)cos(a), (float)sin(a));
    } else if (t < 721){
        int u = t - 481; int n2 = u >> 4, k1 = u & 15;
        double a = -2.0*PI_D*double(n2*k1)/240.0;
        tab[t] = make_float2((float)cos(a), (float)sin(a));
    }
}

// ---------- K1: row rfft, 240 real -> 121 complex. 4 rows/block. ----------
__global__ __launch_bounds__(256) void rowfft(const float* __restrict__ x,
                                              float2* __restrict__ S,
                                              const float2* __restrict__ tab){
    __shared__ float  xs[4*240];
    __shared__ float2 ys[4*240];
    __shared__ float2 tl[721];
    int tid = threadIdx.x;
    for (int e = tid; e < 721; e += 256) tl[e] = tab[e];
    const float2* T16 = tl;
    const float2* T15 = tl + 256;
    const float2* TW  = tl + 481;
    long r0 = (long)blockIdx.x * 4;
    for (int e = tid; e < 960; e += 256) xs[e] = x[r0*240 + e];
    __syncthreads();
    // stage A: y[n2][k1] = sum_n1 x[15*n1+n2] * W16^(n1*k1), then * TW(n2*k1)
    for (int e = tid; e < 960; e += 256){
        int j = e/240, u = e - j*240;
        int n2 = u >> 4, k1 = u & 15;
        float2 acc = make_float2(0.f, 0.f);
        #pragma unroll
        for (int n1 = 0; n1 < 16; n1++){
            float xv = xs[j*240 + 15*n1 + n2];
            float2 t = T16[n1*16 + k1];
            acc.x += xv*t.x; acc.y += xv*t.y;
        }
        ys[e] = cmul(acc, TW[u]);
    }
    __syncthreads();
    // stage B: X[k1+16*k2] = sum_n2 y'[n2][k1] * W15^(n2*k2), keep k<121
    for (int e = tid; e < 484; e += 256){
        int j = e/121, k = e - j*121;
        int k1 = k & 15, k2 = k >> 4;
        float2 acc = make_float2(0.f, 0.f);
        #pragma unroll
        for (int n2 = 0; n2 < 15; n2++)
            cfma(acc, ys[j*240 + n2*16 + k1], T15[n2*15 + k2]);
        S[(r0 + j)*121 + k] = acc;
    }
}

// ---------- K2/K4: FFT along H (length 240 complex), in-place, 11 wf-columns/block ----------
template<bool INV>
__global__ __launch_bounds__(256) void colfft(float2* __restrict__ S,
                                              const float2* __restrict__ tab,
                                              float scale){
    __shared__ float2 xin[2640];
    __shared__ float2 ys2[2640];
    __shared__ float2 tl[721];
    int tid = threadIdx.x;
    for (int e = tid; e < 721; e += 256) tl[e] = tab[e];
    const float2* T16 = tl;
    const float2* T15 = tl + 256;
    const float2* TW  = tl + 481;
    int bid = blockIdx.x;
    int chunk = bid % 11;
    int c = (bid/11) % CCH;
    int b = bid / (11*CCH);
    int wf0 = chunk*11;
    float2* Sbc = S + (long)(b*CCH + c)*PLANE;
    for (int e = tid; e < 2640; e += 256){
        int h = e/11, wi = e - h*11;
        xin[e] = Sbc[h*121 + wf0 + wi];
    }
    __syncthreads();
    for (int e = tid; e < 2640; e += 256){
        int u = e/11, wi = e - u*11;
        int n2 = u >> 4, k1 = u & 15;
        float2 acc = make_float2(0.f, 0.f);
        #pragma unroll
        for (int n1 = 0; n1 < 16; n1++){
            float2 a = xin[(15*n1 + n2)*11 + wi];
            float2 t = T16[n1*16 + k1];
            if (INV) cfmac(acc, a, t); else cfma(acc, a, t);
        }
        float2 tw = TW[u];
        ys2[u*11 + wi] = INV ? cmulc(acc, tw) : cmul(acc, tw);
    }
    __syncthreads();
    for (int e = tid; e < 2640; e += 256){
        int k = e/11, wi = e - k*11;
        int k1 = k & 15, k2 = k >> 4;
        float2 acc = make_float2(0.f, 0.f);
        #pragma unroll
        for (int n2 = 0; n2 < 15; n2++){
            float2 a = ys2[(n2*16 + k1)*11 + wi];
            float2 t = T15[n2*15 + k2];
            if (INV) cfmac(acc, a, t); else cfma(acc, a, t);
        }
        acc.x *= scale; acc.y *= scale;
        Sbc[k*121 + wf0 + wi] = acc;
    }
}

// ---------- K3: block-diagonal complex MLP with sparsity mask, in-place on S ----------
// per block: one (b, n) pair, tile of 64 positions; two 96x96 complex matmuls.
// Double-buffered weight staging: one barrier per 16-wide K chunk, global load
// of chunk c+1 issued before compute of chunk c.
__global__ __launch_bounds__(256) void mix(float2* __restrict__ S,
                                           const float* __restrict__ w1,
                                           const float* __restrict__ b1,
                                           const float* __restrict__ w2,
                                           const float* __restrict__ b2){
    __shared__ float2 Xt[96*64];      // X tile, later reused as T tile  (48 KB)
    __shared__ float2 Wc[2][16*96];   // double-buffered weight K-chunk  (24 KB)
    int tid = threadIdx.x;
    int tx = tid & 15, ty = tid >> 4;
    int bid = blockIdx.x;
    int t  = bid % 454;
    int n  = (bid/454) & 7;
    int b  = bid / (454*8);
    int p0 = t*64;
    int pn = min(64, PLANE - p0);
    float2* Sn = S + (long)(b*CCH + n*BSZ)*PLANE;

    // ---- load X tile (float4 path for full tiles) ----
    if (pn == 64){
        for (int e = tid; e < 3072; e += 256){
            int i = e >> 5, p4 = e & 31;
            ((float4*)Xt)[e] = ((const float4*)(Sn + (long)i*PLANE + p0))[p4];
        }
    } else {
        for (int e = tid; e < 6144; e += 256){
            int i = e >> 6, p = e & 63;
            Xt[e] = (p < pn) ? Sn[(long)i*PLANE + p0 + p] : make_float2(0.f, 0.f);
        }
    }

    float2 acc[4][6];
    #pragma unroll
    for (int r = 0; r < 4; r++)
        #pragma unroll
        for (int s = 0; s < 6; s++) acc[r][s] = make_float2(0.f, 0.f);

    const float2* w1n = (const float2*)(w1 + (long)n*BSZ*BSZ*2);
    const float2* w2n = (const float2*)(w2 + (long)n*BSZ*BSZ*2);

    // ---- GEMM 1: acc[p][o] = sum_i X[i][p] * W1[i][o] ----
    for (int e = tid; e < 768; e += 256)
        ((float4*)Wc[0])[e] = ((const float4*)w1n)[e];
    __syncthreads();   // covers Xt load + chunk 0

    for (int c = 0; c < 6; c++){
        if (c < 5){
            const float4* src = (const float4*)(w1n + (c+1)*16*96);
            for (int e = tid; e < 768; e += 256)
                ((float4*)Wc[(c+1)&1])[e] = src[e];
        }
        const float2* W = Wc[c&1];
        #pragma unroll
        for (int kk = 0; kk < 16; kk++){
            float2 xv[4], wv[6];
            #pragma unroll
            for (int r = 0; r < 4; r++) xv[r] = Xt[(c*16 + kk)*64 + tx + 16*r];
            #pragma unroll
            for (int s = 0; s < 6; s++) wv[s] = W[kk*96 + ty + 16*s];
            #pragma unroll
            for (int r = 0; r < 4; r++)
                #pragma unroll
                for (int s = 0; s < 6; s++) cfma(acc[r][s], xv[r], wv[s]);
        }
        __syncthreads();   // buffer (c+1)&1 fully staged; all reads of chunk c done
    }

    // ---- bias + sparsity mask, write intermediate T into Xt as [o][p] ----
    const float2* b1n = (const float2*)(b1 + (long)n*BSZ*2);
    #pragma unroll
    for (int r = 0; r < 4; r++){
        #pragma unroll
        for (int s = 0; s < 6; s++){
            int o = ty + 16*s, p = tx + 16*r;
            float2 v = acc[r][s];
            float2 bb = b1n[o];
            v.x += bb.x; v.y += bb.y;
            float m2 = v.x*v.x + v.y*v.y + 1e-8f;
            if (!(sqrtf(m2) > 0.01f)) { v.x = 0.f; v.y = 0.f; }
            Xt[o*64 + p] = v;
            acc[r][s] = make_float2(0.f, 0.f);
        }
    }

    // ---- GEMM 2 ----
    for (int e = tid; e < 768; e += 256)
        ((float4*)Wc[0])[e] = ((const float4*)w2n)[e];
    __syncthreads();   // covers Xt(T) writes + chunk 0

    for (int c = 0; c < 6; c++){
        if (c < 5){
            const float4* src = (const float4*)(w2n + (c+1)*16*96);
            for (int e = tid; e < 768; e += 256)
                ((float4*)Wc[(c+1)&1])[e] = src[e];
        }
        const float2* W = Wc[c&1];
        #pragma unroll
        for (int kk = 0; kk < 16; kk++){
            float2 xv[4], wv[6];
            #pragma unroll
            for (int r = 0; r < 4; r++) xv[r] = Xt[(c*16 + kk)*64 + tx + 16*r];
            #pragma unroll
            for (int s = 0; s < 6; s++) wv[s] = W[kk*96 + ty + 16*s];
            #pragma unroll
            for (int r = 0; r < 4; r++)
                #pragma unroll
                for (int s = 0; s < 6; s++) cfma(acc[r][s], xv[r], wv[s]);
        }
        __syncthreads();
    }

    const float2* b2n = (const float2*)(b2 + (long)n*BSZ*2);
    #pragma unroll
    for (int r = 0; r < 4; r++){
        #pragma unroll
        for (int s = 0; s < 6; s++){
            int o = ty + 16*s, p = tx + 16*r;
            if (p < pn){
                float2 v = acc[r][s];
                float2 bb = b2n[o];
                v.x += bb.x; v.y += bb.y;
                Sn[(long)o*PLANE + p0 + p] = v;
            }
        }
    }
}

// ---------- K5: inverse row transform, 121 complex -> 240 real. 4 rows/block. ----------
__global__ __launch_bounds__(256) void irowfft(const float2* __restrict__ S,
                                               float* __restrict__ out,
                                               const float2* __restrict__ tab){
    __shared__ float2 zs[4*240];
    __shared__ float2 ys[4*240];
    __shared__ float2 tl[721];
    int tid = threadIdx.x;
    for (int e = tid; e < 721; e += 256) tl[e] = tab[e];
    const float2* T16 = tl;
    const float2* T15 = tl + 256;
    const float2* TW  = tl + 481;
    long r0 = (long)blockIdx.x * 4;
    for (int e = tid; e < 484; e += 256){
        int j = e/121, k = e - j*121;
        zs[j*240 + k] = S[(r0 + j)*121 + k];
    }
    __syncthreads();
    // Hermitian expansion: z[k] = conj(z[240-k]) for k in [121,240)
    for (int e = tid; e < 476; e += 256){
        int j = e/119, kk = e - j*119;
        int k = 121 + kk;
        float2 v = zs[j*240 + 240 - k];
        zs[j*240 + k] = make_float2(v.x, -v.y);
    }
    __syncthreads();
    for (int e = tid; e < 960; e += 256){
        int j = e/240, u = e - j*240;
        int n2 = u >> 4, k1 = u & 15;
        float2 acc = make_float2(0.f, 0.f);
        #pragma unroll
        for (int n1 = 0; n1 < 16; n1++)
            cfmac(acc, zs[j*240 + 15*n1 + n2], T16[n1*16 + k1]);
        ys[j*240 + u] = cmulc(acc, TW[u]);
    }
    __syncthreads();
    for (int e = tid; e < 960; e += 256){
        int j = e/240, nn = e - j*240;
        int k1 = nn & 15, k2 = nn >> 4;
        float2 acc = make_float2(0.f, 0.f);
        #pragma unroll
        for (int n2 = 0; n2 < 15; n2++)
            cfmac(acc, ys[j*240 + n2*16 + k1], T15[n2*15 + k2]);
        out[(r0 + j)*240 + nn] = acc.x * (1.f/240.f);
    }
}

extern "C" void kernel_launch(void* const* d_in, const int* in_sizes, int n_in,
                              void* d_out, int out_size, void* d_ws, size_t ws_size,
                              hipStream_t stream){
    const float* x  = (const float*)d_in[0];
    const float* w1 = (const float*)d_in[1];
    const float* b1 = (const float*)d_in[2];
    const float* w2 = (const float*)d_in[3];
    const float* b2 = (const float*)d_in[4];
    float* out = (float*)d_out;

    // ws layout: [0, 356843520) spectrum S (float2, B*C*H*WF), then tables
    float2* S   = (float2*)d_ws;
    float2* tab = (float2*)((char*)d_ws + (size_t)356843520);

    init_tables<<<1, 768, 0, stream>>>(tab);
    rowfft<<<NROWS/4, 256, 0, stream>>>(x, S, tab);                         // 92160
    colfft<false><<<BATCH*CCH*11, 256, 0, stream>>>(S, tab, 1.f/240.f);     // 16896
    mix<<<BATCH*NBLK*454, 256, 0, stream>>>(S, w1, b1, w2, b2);             // 7264
    colfft<true><<<BATCH*CCH*11, 256, 0, stream>>>(S, tab, 1.f);            // 16896
    irowfft<<<NROWS/4, 256, 0, stream>>>(S, out, tab);                      // 92160
}